// Round 5
// baseline (1542.710 us; speedup 1.0000x reference)
//
#include <hip/hip_runtime.h>
#include <math.h>

#define N_NODES 50000
#define N_EDGES 100000
#define H 768
#define NH 12
#define HD 64
#define NG 64
#define NC 10
#define H2 384
#define PCH 32   // pooling chunks per graph
#define NSB 196  // scan blocks = cdiv(N_NODES,256)
#define GBLK 85  // gemm blocks per col-group (3 groups = 255 blocks)

typedef _Float16 h8  __attribute__((ext_vector_type(8)));   // 8 fp16 (4 VGPR)
typedef _Float16 h4v __attribute__((ext_vector_type(4)));
typedef float    ffrag __attribute__((ext_vector_type(4))); // MFMA acc

// ---------------- static device scratch ----------------
__device__ _Float16 g_ah[(size_t)N_NODES * H];     // GEMM input acts fp16
__device__ _Float16 g_ch[(size_t)N_NODES * H];     // GEMM output / gather input fp16
__device__ _Float16 g_wh[4 * H * H];               // 4 weights^T fp16 [N][K]
__device__ float    g_dinv[N_NODES];
__device__ int      g_degi[N_NODES];
__device__ int      g_bsum[256];
__device__ int      g_boff[256];
__device__ int      g_cursor[N_NODES];
__device__ int      g_rowptr[N_NODES + 1];
__device__ int      g_csrsrc[N_EDGES];
__device__ float    g_aS[(size_t)N_NODES * NH];
__device__ float    g_aD[(size_t)N_NODES * NH];
__device__ float    g_selfc[(size_t)N_NODES * NH]; // GAT self-coefficient
__device__ float    g_coef[(size_t)N_EDGES * NH];  // GAT per-edge coefficient (4.8 MB)
__device__ float    g_ppool[(size_t)NG * PCH * H]; // pooling partials (6.3 MB)

__device__ inline int clampi(int v, int hi) { return (v < 0) ? 0 : (v >= hi ? hi - 1 : v); }

// async global->LDS, 16B per lane: lane i writes lds_base + i*16 (wave-uniform base)
__device__ inline void gload_lds16(const _Float16* g, _Float16* s) {
    __builtin_amdgcn_global_load_lds(
        (const __attribute__((address_space(1))) void*)g,
        (__attribute__((address_space(3))) void*)s, 16, 0, 0);
}

// ---------------- CSR build ----------------
__global__ void fill_i32(int* p, int n, int v) {
    int i = blockIdx.x * blockDim.x + threadIdx.x;
    if (i < n) p[i] = v;
}

__global__ void count_deg(const int* __restrict__ dst, int* __restrict__ degi) {
    int e = blockIdx.x * blockDim.x + threadIdx.x;
    if (e < N_EDGES) atomicAdd(&degi[clampi(dst[e], N_NODES)], 1);
}

// hierarchical scan (r13-verified)
__global__ __launch_bounds__(256) void scan1(const int* __restrict__ degi, int* __restrict__ bsum) {
    __shared__ int s[256];
    int b = blockIdx.x, t = threadIdx.x;
    int idx = b * 256 + t;
    s[t] = (idx < N_NODES) ? degi[idx] : 0;
    __syncthreads();
    for (int off = 128; off > 0; off >>= 1) {
        if (t < off) s[t] += s[t + off];
        __syncthreads();
    }
    if (t == 0) bsum[b] = s[0];
}

__global__ __launch_bounds__(256) void scan2(const int* __restrict__ bsum, int* __restrict__ boff,
                                             int* __restrict__ rowptr) {
    __shared__ int s[256];
    int t = threadIdx.x;
    int v = (t < NSB) ? bsum[t] : 0;
    s[t] = v;
    __syncthreads();
    for (int off = 1; off < 256; off <<= 1) {
        int x = (t >= off) ? s[t - off] : 0;
        __syncthreads();
        s[t] += x;
        __syncthreads();
    }
    if (t < NSB) boff[t] = s[t] - v;
    if (t == NSB - 1) rowptr[N_NODES] = s[t];
}

__global__ __launch_bounds__(256) void scan3(const int* __restrict__ degi, const int* __restrict__ boff,
                                             int* __restrict__ rowptr, int* __restrict__ cursor,
                                             float* __restrict__ dinv) {
    __shared__ int s[256];
    int b = blockIdx.x, t = threadIdx.x;
    int idx = b * 256 + t;
    int v = (idx < N_NODES) ? degi[idx] : 0;
    s[t] = v;
    __syncthreads();
    for (int off = 1; off < 256; off <<= 1) {
        int x = (t >= off) ? s[t - off] : 0;
        __syncthreads();
        s[t] += x;
        __syncthreads();
    }
    if (idx < N_NODES) {
        int excl = s[t] - v + boff[b];
        rowptr[idx] = excl;
        cursor[idx] = excl;
        dinv[idx] = rsqrtf((float)v + 1.0f);   // +1 = self-loop
    }
}

__global__ void bin_edges(const int* __restrict__ src, const int* __restrict__ dst,
                          int* __restrict__ cursor, int* __restrict__ csrsrc) {
    int e = blockIdx.x * blockDim.x + threadIdx.x;
    if (e >= N_EDGES) return;
    int d = clampi(dst[e], N_NODES);
    int pos = atomicAdd(&cursor[d], 1);
    if (pos >= 0 && pos < N_EDGES) csrsrc[pos] = clampi(src[e], N_NODES);
}

// all 4 big weights: w[K][N] fp32 -> transposed fp16 [N][K], one launch
__global__ void split_wT4(const float* __restrict__ w2, const float* __restrict__ w3,
                          const float* __restrict__ wg1, const float* __restrict__ wg2,
                          _Float16* __restrict__ out) {
    int idx = blockIdx.x * blockDim.x + threadIdx.x;
    if (idx >= 4 * H * H) return;
    int l = idx / (H * H), r = idx % (H * H);
    const float* w = (l == 0) ? w2 : (l == 1) ? w3 : (l == 2) ? wg1 : wg2;
    int n = r % H, k = r / H;
    out[(size_t)l * H * H + (size_t)n * H + k] = (_Float16)w[(size_t)k * H + n];
}

// ---- fused GCN1: aggregate x (3-dim!) then matvec w1 + bias + relu + fp16 ----
__global__ void gcn1_fused(const int* __restrict__ rowptr, const int* __restrict__ csrsrc,
                           const float* __restrict__ x, const float* __restrict__ dinv,
                           const float* __restrict__ w1, const float* __restrict__ b1,
                           _Float16* __restrict__ hi) {
    int d = blockIdx.x * 2 + (threadIdx.x / 96);
    int t = threadIdx.x % 96;
    if (d >= N_NODES) return;
    float dd = dinv[d];
    float c = dd * dd;
    float s0 = x[d*3] * c, s1 = x[d*3+1] * c, s2 = x[d*3+2] * c;
    int beg = rowptr[d], end = rowptr[d + 1];
    for (int i = beg; i < end; i++) {
        int s = csrsrc[i];
        float cc = dinv[s] * dd;
        s0 += x[s*3] * cc; s1 += x[s*3+1] * cc; s2 += x[s*3+2] * cc;
    }
    int j0 = t * 8;
    h8 o;
    #pragma unroll
    for (int k = 0; k < 8; k++) {
        int j = j0 + k;
        float v = s0 * w1[j] + s1 * w1[H + j] + s2 * w1[2*H + j] + b1[j];
        o[k] = (_Float16)fmaxf(v, 0.f);
    }
    ((h8*)(hi + (size_t)d * H))[t] = o;
}

// -- persistent-B fp16 MFMA GEMM ----------------------------------------------
// r23: R0-R4 post-mortem -- three different schedules at two occupancies all
// give 543 TF / 22% MfmaUtil, so the limiter is the TILING's data movement:
// (a) VMEM requests 687 MB/GEMM (A-strip read 6x, B re-read per block),
// (b) LDS reads 128 KB per CU per K-step vs ~112 B/cyc LDS ceiling.
// Fix: B (1.18 MB total) lives in REGISTERS. Block = 16 waves (1024 thr),
// 3 col-groups x 85 blocks = 255 (single round, no tail rounds). Each block:
// cols = colgrp*256 + wave-grid (wm 0..1 x wn 0..7), wave tile 64 rows x 32
// cols; per wave 48 persistent B-frags (2 cols-of-16 x 24 K-slices = 192 VGPR,
// static indices via fully unrolled K loop -- rule #20). A streams through a
// ring-4 LDS (4 x 16 KB), 1 gload_lds/wave/K-step, prefetch distance 3,
// uniform vmcnt(2) + 1 barrier per K-step (buffer idx kt&3 is static since
// 12 % 4 == 0). B ds_reads eliminated; VMEM traffic 687 -> ~310 MB.
// Blocks sweep 4-5 consecutive 128-row strips (B regs amortized across strips).
// GAT alpha fused per strip; head = 2 waves -> combine via 8 KB LDS scratch.
__global__ __launch_bounds__(1024, 4) void gemm_f16(const _Float16* __restrict__ a,
                                                    const _Float16* __restrict__ bt,
                                                    _Float16* __restrict__ C, int M,
                                                    const float* __restrict__ asf,
                                                    const float* __restrict__ adf,
                                                    float* __restrict__ aS,
                                                    float* __restrict__ aD) {
    __shared__ alignas(16) _Float16 As[4][8192];   // ring-4 A[128x64] swizzled
    __shared__ float alsS[16][64];                 // alpha partials (S)
    __shared__ float alsD[16][64];                 // alpha partials (D)

    int tid = threadIdx.x;
    int wave = tid >> 6, lane = tid & 63;
    int quad = lane >> 4, l16 = lane & 15;
    int wm = wave >> 3, wn = wave & 7;            // 2 row-waves x 8 col-waves

    int colgrp = blockIdx.x / GBLK;               // 0..2 -> cols colgrp*256
    int b      = blockIdx.x % GBLK;               // 0..84
    // 391 strips of 128 rows = 85*4 + 51: first 51 blocks take 5 strips
    int cnt = (b < 51) ? 5 : 4;
    int s0  = b * 4 + (b < 51 ? b : 51);
    int col0 = colgrp * 256;
    int cw   = col0 + wn * 32;                    // wave's 32-col slice

    // ---- persistent B fragments: bf[j][ks], ks = K-slice of 32 (0..23) ----
    // frag = bt[col][ks*32 + quad*8 .. +8]; same layout the LDS path produced.
    h8 bf0[24], bf1[24];
    {
        const _Float16* b0p = bt + (size_t)(cw + l16) * H + quad * 8;
        const _Float16* b1p = bt + (size_t)(cw + 16 + l16) * H + quad * 8;
        #pragma unroll
        for (int ks = 0; ks < 24; ks++) {
            bf0[ks] = *reinterpret_cast<const h8*>(b0p + ks * 32);
            bf1[ks] = *reinterpret_cast<const h8*>(b1p + ks * 32);
        }
    }

    // ---- A staging: 1 gload/wave/K-step, rows wave*8..+8, pre-swizzled src --
    int lr = lane >> 3;                // row within 8-row group
    int cg = (lane & 7) ^ lr;          // pre-swizzled source chunk
    int stoff = wave * 8 * 64;         // LDS dst (halfs), lane offset implicit
    int arow  = wave * 8 + lr;         // row within strip
    // fragment read offsets: offA[i][kk], XOR swizzle chunk' = (kk*4+quad)^(row&7)
    int swz = l16 & 7;
    int offA[4][2];
    #pragma unroll
    for (int i = 0; i < 4; i++)
        #pragma unroll
        for (int kk = 0; kk < 2; kk++)
            offA[i][kk] = (wm * 64 + i * 16 + l16) * 64 + (((kk * 4 + quad) ^ swz) * 8);

    // alpha coefficients (uniform across strips)
    float asc0 = 0.f, asc1 = 0.f, adc0 = 0.f, adc1 = 0.f;
    if (asf) {
        asc0 = asf[cw + l16];      asc1 = asf[cw + 16 + l16];
        adc0 = adf[cw + l16];      adc1 = adf[cw + 16 + l16];
    }

    ffrag acc[4][2];
    #pragma unroll
    for (int i = 0; i < 4; i++)
        #pragma unroll
        for (int j = 0; j < 2; j++) { ffrag z = {0.f, 0.f, 0.f, 0.f}; acc[i][j] = z; }

    // ---- prologue: stage tiles (s0,0),(s0,1),(s0,2) into bufs 0,1,2 ----
    {
        int r = s0 * 128 + arow; if (r >= M) r = M - 1;
        const _Float16* ap = a + (size_t)r * H + cg * 8;
        gload_lds16(ap,        &As[0][0] + stoff);
        gload_lds16(ap + 64,   &As[1][0] + stoff);
        gload_lds16(ap + 128,  &As[2][0] + stoff);
    }
    asm volatile("s_waitcnt vmcnt(2)" ::: "memory");   // B frags + tile 0 resident
    __builtin_amdgcn_s_barrier();

    int row0 = s0 * 128;
    #pragma unroll 1
    for (int sdx = 0; sdx < cnt; sdx++) {
        #pragma unroll
        for (int kt = 0; kt < 12; kt++) {
            // prefetch tile kt+3 (rolls into next strip for kt >= 9); clamped
            {
                int prow = row0 + ((kt >= 9) ? 128 : 0) + arow;
                if (prow >= M) prow = M - 1;
                int pkk = (kt >= 9) ? (kt - 9) : (kt + 3);
                gload_lds16(a + (size_t)prow * H + pkk * 64 + cg * 8,
                            &As[(kt + 3) & 3][0] + stoff);
            }
            // A fragments of tile kt from ring buffer (static index kt&3)
            const _Float16* pc = &As[kt & 3][0];
            h8 fa[4][2];
            #pragma unroll
            for (int i = 0; i < 4; i++)
                #pragma unroll
                for (int kk = 0; kk < 2; kk++)
                    fa[i][kk] = *reinterpret_cast<const h8*>(pc + offA[i][kk]);
            asm volatile("s_waitcnt lgkmcnt(0)" ::: "memory");
            __builtin_amdgcn_sched_barrier(0);
            __builtin_amdgcn_s_setprio(1);
            #pragma unroll
            for (int kk = 0; kk < 2; kk++)
                #pragma unroll
                for (int i = 0; i < 4; i++) {
                    acc[i][0] = __builtin_amdgcn_mfma_f32_16x16x32_f16(fa[i][kk], bf0[kt * 2 + kk], acc[i][0], 0, 0, 0);
                    acc[i][1] = __builtin_amdgcn_mfma_f32_16x16x32_f16(fa[i][kk], bf1[kt * 2 + kk], acc[i][1], 0, 0, 0);
                }
            __builtin_amdgcn_s_setprio(0);
            // retire: tile kt+1 landed (2 newest loads stay in flight)
            asm volatile("s_waitcnt vmcnt(2)" ::: "memory");
            __builtin_amdgcn_sched_barrier(0);
            __builtin_amdgcn_s_barrier();
        }

        // ---- strip epilogue: C write, alpha, reset ----
        #pragma unroll
        for (int i = 0; i < 4; i++)
            #pragma unroll
            for (int r = 0; r < 4; r++) {
                int row = row0 + wm * 64 + i * 16 + quad * 4 + r;
                if (row < M) {
                    C[(size_t)row * H + cw + l16]      = (_Float16)acc[i][0][r];
                    C[(size_t)row * H + cw + 16 + l16] = (_Float16)acc[i][1][r];
                }
            }

        if (asf) {
            // per-lane partial over this wave's 32 cols, reduce 16-lane groups
            #pragma unroll
            for (int i = 0; i < 4; i++)
                #pragma unroll
                for (int r = 0; r < 4; r++) {
                    float ps = acc[i][0][r] * asc0 + acc[i][1][r] * asc1;
                    float pd = acc[i][0][r] * adc0 + acc[i][1][r] * adc1;
                    ps += __shfl_xor(ps, 1);  pd += __shfl_xor(pd, 1);
                    ps += __shfl_xor(ps, 2);  pd += __shfl_xor(pd, 2);
                    ps += __shfl_xor(ps, 4);  pd += __shfl_xor(pd, 4);
                    ps += __shfl_xor(ps, 8);  pd += __shfl_xor(pd, 8);
                    if (l16 == 0) {
                        alsS[wave][i * 16 + quad * 4 + r] = ps;
                        alsD[wave][i * 16 + quad * 4 + r] = pd;
                    }
                }
            __syncthreads();
            if ((wn & 1) == 0) {            // even wave of head pair combines
                float s = alsS[wave][lane] + alsS[wave + 1][lane];
                float d = alsD[wave][lane] + alsD[wave + 1][lane];
                int row = row0 + wm * 64 + lane;
                int head = colgrp * 4 + (wn >> 1);
                if (row < M) {
                    aS[row * NH + head] = s;
                    aD[row * NH + head] = d;
                }
            }
            __syncthreads();
        }

        #pragma unroll
        for (int i = 0; i < 4; i++)
            #pragma unroll
            for (int j = 0; j < 2; j++) { ffrag z = {0.f, 0.f, 0.f, 0.f}; acc[i][j] = z; }
        row0 += 128;
    }
}

// ------- fused GCN gather: 2 nodes/block, 16B h8 loads (r14-verified) --------
__global__ void gcn_gather(const int* __restrict__ rowptr, const int* __restrict__ csrsrc,
                           const _Float16* __restrict__ h, const float* __restrict__ dinv,
                           const float* __restrict__ bias, _Float16* __restrict__ hi) {
    int d = blockIdx.x * 2 + (threadIdx.x / 96);
    int t = threadIdx.x % 96;   // h8-chunk index (96 x 8 halves = 768)
    if (d >= N_NODES) return;
    float dd = dinv[d];
    float c = dd * dd;
    h8 v = ((const h8*)(h + (size_t)d * H))[t];
    float acc[8];
    #pragma unroll
    for (int k = 0; k < 8; k++) acc[k] = (float)v[k] * c;
    int beg = rowptr[d], end = rowptr[d + 1];
    for (int i = beg; i < end; i++) {
        int s = csrsrc[i];
        float cc = dinv[s] * dd;
        h8 u = ((const h8*)(h + (size_t)s * H))[t];
        #pragma unroll
        for (int k = 0; k < 8; k++) acc[k] += (float)u[k] * cc;
    }
    float4 b0 = ((const float4*)bias)[2 * t];
    float4 b1 = ((const float4*)bias)[2 * t + 1];
    h8 o;
    o[0] = (_Float16)fmaxf(acc[0] + b0.x, 0.f);
    o[1] = (_Float16)fmaxf(acc[1] + b0.y, 0.f);
    o[2] = (_Float16)fmaxf(acc[2] + b0.z, 0.f);
    o[3] = (_Float16)fmaxf(acc[3] + b0.w, 0.f);
    o[4] = (_Float16)fmaxf(acc[4] + b1.x, 0.f);
    o[5] = (_Float16)fmaxf(acc[5] + b1.y, 0.f);
    o[6] = (_Float16)fmaxf(acc[6] + b1.z, 0.f);
    o[7] = (_Float16)fmaxf(acc[7] + b1.w, 0.f);
    ((h8*)(hi + (size_t)d * H))[t] = o;
}

__device__ inline float lrelu(float v) { return (v > 0.f) ? v : 0.2f * v; }

// ---- GAT softmax stats: one thread per (node, head) (r18-verified) ----
__global__ void gat_stats(const int* __restrict__ rowptr, const int* __restrict__ csrsrc,
                          const float* __restrict__ aS, const float* __restrict__ aD,
                          float* __restrict__ selfc, float* __restrict__ coef) {
    int idx = blockIdx.x * blockDim.x + threadIdx.x;
    if (idx >= N_NODES * NH) return;
    int d = idx / NH, hh = idx % NH;
    int beg = rowptr[d], end = rowptr[d + 1];
    float adv = aD[idx];
    float eself = lrelu(aS[idx] + adv);
    float m = eself;
    for (int i = beg; i < end; i++)
        m = fmaxf(m, lrelu(aS[csrsrc[i] * NH + hh] + adv));
    float ssum = __expf(eself - m);
    for (int i = beg; i < end; i++)
        ssum += __expf(lrelu(aS[csrsrc[i] * NH + hh] + adv) - m);
    float inv = 1.0f / ssum;
    selfc[idx] = __expf(eself - m) * inv;
    for (int i = beg; i < end; i++)
        coef[(size_t)i * NH + hh] = __expf(lrelu(aS[csrsrc[i] * NH + hh] + adv) - m) * inv;
}

// fused GAT aggregation: single pass, precomputed coefficients; fp16 out.
__global__ void gat_gather(const int* __restrict__ rowptr, const int* __restrict__ csrsrc,
                           const _Float16* __restrict__ h, const float* __restrict__ selfc,
                           const float* __restrict__ coef, const float* __restrict__ bias,
                           _Float16* __restrict__ hi, int relu) {
    int d = blockIdx.x * 2 + (threadIdx.x / 96);
    int t = threadIdx.x % 96;
    if (d >= N_NODES) return;
    int hh = t >> 3;
    int beg = rowptr[d], end = rowptr[d + 1];
    float cself = selfc[d * NH + hh];
    h8 v = ((const h8*)(h + (size_t)d * H))[t];
    float acc[8];
    #pragma unroll
    for (int k = 0; k < 8; k++) acc[k] = (float)v[k] * cself;
    for (int i = beg; i < end; i++) {
        int s = csrsrc[i];
        float c = coef[(size_t)i * NH + hh];
        h8 u = ((const h8*)(h + (size_t)s * H))[t];
        #pragma unroll
        for (int k = 0; k < 8; k++) acc[k] += (float)u[k] * c;
    }
    float4 b0 = ((const float4*)bias)[2 * t];
    float4 b1 = ((const float4*)bias)[2 * t + 1];
    acc[0] += b0.x; acc[1] += b0.y; acc[2] += b0.z; acc[3] += b0.w;
    acc[4] += b1.x; acc[5] += b1.y; acc[6] += b1.z; acc[7] += b1.w;
    if (relu) {
        #pragma unroll
        for (int k = 0; k < 8; k++) acc[k] = fmaxf(acc[k], 0.f);
    }
    h8 o;
    #pragma unroll
    for (int k = 0; k < 8; k++) o[k] = (_Float16)acc[k];
    ((h8*)(hi + (size_t)d * H))[t] = o;
}

// ---------------- pooling (batch is sorted), two-stage + fused mlp1+mlp2 ------
__device__ inline int lower_bound_i(const int* b, int n, int key) {
    int lo = 0, hi = n;
    while (lo < hi) { int mid = (lo + hi) >> 1; if (b[mid] < key) lo = mid + 1; else hi = mid; }
    return lo;
}

__global__ void pool_partial(const int* __restrict__ batch, const _Float16* __restrict__ h,
                             float* __restrict__ ppool) {
    int g = blockIdx.x / PCH, c = blockIdx.x % PCH;
    int t = threadIdx.x;   // 0..191, h4v chunks
    int lo = lower_bound_i(batch, N_NODES, g);
    int hi = lower_bound_i(batch, N_NODES, g + 1);
    int len = hi - lo;
    int chunk = (len + PCH - 1) / PCH;
    int s = lo + c * chunk;
    int e = s + chunk; if (e > hi) e = hi;
    float4 a = {0, 0, 0, 0};
    for (int n = s; n < e; n++) {
        h4v v = ((const h4v*)(h + (size_t)n * H))[t];
        a.x += (float)v[0]; a.y += (float)v[1]; a.z += (float)v[2]; a.w += (float)v[3];
    }
    ((float4*)(ppool + (size_t)blockIdx.x * H))[t] = a;
}

// reduce partials -> mean row -> z = relu(row@wc1+bc1) -> logits = z@wc2+bc2
__global__ __launch_bounds__(384) void pool_mlp(const int* __restrict__ batch,
                                                const float* __restrict__ ppool,
                                                const float* __restrict__ wc1,
                                                const float* __restrict__ bc1,
                                                const float* __restrict__ wc2,
                                                const float* __restrict__ bc2,
                                                float* __restrict__ out) {
    __shared__ float row[H];
    __shared__ float z[H2];
    int g = blockIdx.x, t = threadIdx.x;   // 384 threads
    int lo = lower_bound_i(batch, N_NODES, g);
    int hi = lower_bound_i(batch, N_NODES, g + 1);
    float inv = 1.0f / fmaxf((float)(hi - lo), 1.0f);
    for (int c0 = t; c0 < H; c0 += 384) {
        float a = 0.f;
        for (int c = 0; c < PCH; c++) a += ppool[(size_t)(g * PCH + c) * H + c0];
        row[c0] = a * inv;
    }
    __syncthreads();
    float acc = bc1[t];
    for (int k = 0; k < H; k++) acc += row[k] * wc1[(size_t)k * H2 + t];
    z[t] = fmaxf(acc, 0.f);
    __syncthreads();
    if (t < NC) {
        float l = bc2[t];
        for (int k = 0; k < H2; k++) l += z[k] * wc2[(size_t)k * NC + t];
        out[g * NC + t] = l;
    }
}

// ---------------- launch ----------------
extern "C" void kernel_launch(void* const* d_in, const int* in_sizes, int n_in,
                              void* d_out, int out_size, void* d_ws, size_t ws_size,
                              hipStream_t stream) {
    (void)d_ws; (void)ws_size;
    const float* x     = (const float*)d_in[0];
    const int*   ei    = (const int*)d_in[1];
    const int*   batch = (const int*)d_in[2];
    const float* w1  = (const float*)d_in[3];  const float* b1  = (const float*)d_in[4];
    const float* w2  = (const float*)d_in[5];  const float* b2  = (const float*)d_in[6];
    const float* w3  = (const float*)d_in[7];  const float* b3  = (const float*)d_in[8];
    const float* wg1 = (const float*)d_in[9];  const float* as1 = (const float*)d_in[10];
    const float* ad1 = (const float*)d_in[11]; const float* bg1 = (const float*)d_in[12];
    const float* wg2 = (const float*)d_in[13]; const float* as2 = (const float*)d_in[14];
    const float* ad2 = (const float*)d_in[15]; const float* bg2 = (const float*)d_in[16];
    const float* wc1 = (const float*)d_in[17]; const float* bc1 = (const float*)d_in[18];
    const float* wc2 = (const float*)d_in[19]; const float* bc2 = (const float*)d_in[20];

    const int* srcp = ei;            // edge_index[0]
    const int* dstp = ei + N_EDGES;  // edge_index[1]

    float *dinv, *aS, *aD, *selfc, *coef, *ppool;
    _Float16 *ah, *ch, *wh;
    int *degi, *bsum, *boff, *cursor, *rowptr, *csrsrc;
    hipGetSymbolAddress((void**)&ah,     HIP_SYMBOL(g_ah));
    hipGetSymbolAddress((void**)&ch,     HIP_SYMBOL(g_ch));
    hipGetSymbolAddress((void**)&wh,     HIP_SYMBOL(g_wh));
    hipGetSymbolAddress((void**)&dinv,   HIP_SYMBOL(g_dinv));
    hipGetSymbolAddress((void**)&degi,   HIP_SYMBOL(g_degi));
    hipGetSymbolAddress((void**)&bsum,   HIP_SYMBOL(g_bsum));
    hipGetSymbolAddress((void**)&boff,   HIP_SYMBOL(g_boff));
    hipGetSymbolAddress((void**)&cursor, HIP_SYMBOL(g_cursor));
    hipGetSymbolAddress((void**)&rowptr, HIP_SYMBOL(g_rowptr));
    hipGetSymbolAddress((void**)&csrsrc, HIP_SYMBOL(g_csrsrc));
    hipGetSymbolAddress((void**)&aS,     HIP_SYMBOL(g_aS));
    hipGetSymbolAddress((void**)&aD,     HIP_SYMBOL(g_aD));
    hipGetSymbolAddress((void**)&selfc,  HIP_SYMBOL(g_selfc));
    hipGetSymbolAddress((void**)&coef,   HIP_SYMBOL(g_coef));
    hipGetSymbolAddress((void**)&ppool,  HIP_SYMBOL(g_ppool));

    auto cdiv = [](int a, int b) { return (a + b - 1) / b; };
    int ggrid = 3 * GBLK;                                      // 255 persistent blocks
    int ngath = cdiv(N_NODES, 2);                              // 25000
    size_t HH = (size_t)H * H;

    // ---- weight transpose+cast, one launch, off the critical path ----
    split_wT4<<<cdiv(4*H*H,256),256,0,stream>>>(w2, w3, wg1, wg2, wh);

    // ---- CSR build (hierarchical scan) ----
    fill_i32<<<cdiv(N_NODES,256),256,0,stream>>>(degi, N_NODES, 0);
    count_deg<<<cdiv(N_EDGES,256),256,0,stream>>>(dstp, degi);
    scan1<<<NSB,256,0,stream>>>(degi, bsum);
    scan2<<<1,256,0,stream>>>(bsum, boff, rowptr);
    scan3<<<NSB,256,0,stream>>>(degi, boff, rowptr, cursor, dinv);
    bin_edges<<<cdiv(N_EDGES,256),256,0,stream>>>(srcp, dstp, cursor, csrsrc);

    // ---- GCN1: aggregate-first (3-dim) + matvec, single kernel ----
    gcn1_fused<<<ngath,192,0,stream>>>(rowptr, csrsrc, x, dinv, w1, b1, ah);

    // ---- GCN2 ----
    gemm_f16<<<ggrid,1024,0,stream>>>(ah, wh + 0*HH, ch, N_NODES,
                                      (const float*)nullptr, (const float*)nullptr,
                                      (float*)nullptr, (float*)nullptr);
    gcn_gather<<<ngath,192,0,stream>>>(rowptr, csrsrc, ch, dinv, b2, ah);

    // ---- GCN3 ----
    gemm_f16<<<ggrid,1024,0,stream>>>(ah, wh + 1*HH, ch, N_NODES,
                                      (const float*)nullptr, (const float*)nullptr,
                                      (float*)nullptr, (float*)nullptr);
    gcn_gather<<<ngath,192,0,stream>>>(rowptr, csrsrc, ch, dinv, b3, ah);

    // ---- GAT1 (alpha fused into GEMM; softmax precomputed; 1-pass gather) ----
    gemm_f16<<<ggrid,1024,0,stream>>>(ah, wh + 2*HH, ch, N_NODES, as1, ad1, aS, aD);
    gat_stats<<<cdiv(N_NODES*NH,256),256,0,stream>>>(rowptr, csrsrc, aS, aD, selfc, coef);
    gat_gather<<<ngath,192,0,stream>>>(rowptr, csrsrc, ch, selfc, coef, bg1, ah, 1);

    // ---- GAT2 (no relu; fp16 out -> fp16 pooling) ----
    gemm_f16<<<ggrid,1024,0,stream>>>(ah, wh + 3*HH, ch, N_NODES, as2, ad2, aS, aD);
    gat_stats<<<cdiv(N_NODES*NH,256),256,0,stream>>>(rowptr, csrsrc, aS, aD, selfc, coef);
    gat_gather<<<ngath,192,0,stream>>>(rowptr, csrsrc, ch, selfc, coef, bg2, ah, 0);

    // ---- pool (two-stage; stage-2 fused with mlp1+mlp2) ----
    pool_partial<<<NG*PCH,192,0,stream>>>(batch, ah, ppool);
    pool_mlp<<<NG,384,0,stream>>>(batch, ppool, wc1, bc1, wc2, bc2, (float*)d_out);
}

// Round 6
// 857.462 us; speedup vs baseline: 1.7992x; 1.7992x over previous
//
#include <hip/hip_runtime.h>
#include <math.h>

#define N_NODES 50000
#define N_EDGES 100000
#define H 768
#define NH 12
#define HD 64
#define NG 64
#define NC 10
#define H2 384
#define PCH 32   // pooling chunks per graph
#define NSB 196  // scan blocks = cdiv(N_NODES,256)

typedef _Float16 h8  __attribute__((ext_vector_type(8)));   // 8 fp16 (4 VGPR)
typedef _Float16 h4v __attribute__((ext_vector_type(4)));
typedef float    ffrag __attribute__((ext_vector_type(4))); // MFMA acc

// ---------------- static device scratch ----------------
__device__ _Float16 g_ah[(size_t)N_NODES * H];     // GEMM input acts fp16
__device__ _Float16 g_ch[(size_t)N_NODES * H];     // GEMM output / gather input fp16
__device__ _Float16 g_wh[4 * H * H];               // 4 weights^T fp16 [N][K]
__device__ float    g_dinv[N_NODES];
__device__ int      g_degi[N_NODES];
__device__ int      g_bsum[256];
__device__ int      g_boff[256];
__device__ int      g_cursor[N_NODES];
__device__ int      g_rowptr[N_NODES + 1];
__device__ int      g_csrsrc[N_EDGES];
__device__ float    g_aS[(size_t)N_NODES * NH];
__device__ float    g_aD[(size_t)N_NODES * NH];
__device__ float    g_selfc[(size_t)N_NODES * NH]; // GAT self-coefficient
__device__ float    g_coef[(size_t)N_EDGES * NH];  // GAT per-edge coefficient (4.8 MB)
__device__ float    g_ppool[(size_t)NG * PCH * H]; // pooling partials (6.3 MB)

__device__ inline int clampi(int v, int hi) { return (v < 0) ? 0 : (v >= hi ? hi - 1 : v); }

// async global->LDS, 16B per lane: lane i writes lds_base + i*16 (wave-uniform base)
__device__ inline void gload_lds16(const _Float16* g, _Float16* s) {
    __builtin_amdgcn_global_load_lds(
        (const __attribute__((address_space(1))) void*)g,
        (__attribute__((address_space(3))) void*)s, 16, 0, 0);
}

// ---------------- CSR build ----------------
__global__ void fill_i32(int* p, int n, int v) {
    int i = blockIdx.x * blockDim.x + threadIdx.x;
    if (i < n) p[i] = v;
}

__global__ void count_deg(const int* __restrict__ dst, int* __restrict__ degi) {
    int e = blockIdx.x * blockDim.x + threadIdx.x;
    if (e < N_EDGES) atomicAdd(&degi[clampi(dst[e], N_NODES)], 1);
}

// hierarchical scan (r13-verified)
__global__ __launch_bounds__(256) void scan1(const int* __restrict__ degi, int* __restrict__ bsum) {
    __shared__ int s[256];
    int b = blockIdx.x, t = threadIdx.x;
    int idx = b * 256 + t;
    s[t] = (idx < N_NODES) ? degi[idx] : 0;
    __syncthreads();
    for (int off = 128; off > 0; off >>= 1) {
        if (t < off) s[t] += s[t + off];
        __syncthreads();
    }
    if (t == 0) bsum[b] = s[0];
}

__global__ __launch_bounds__(256) void scan2(const int* __restrict__ bsum, int* __restrict__ boff,
                                             int* __restrict__ rowptr) {
    __shared__ int s[256];
    int t = threadIdx.x;
    int v = (t < NSB) ? bsum[t] : 0;
    s[t] = v;
    __syncthreads();
    for (int off = 1; off < 256; off <<= 1) {
        int x = (t >= off) ? s[t - off] : 0;
        __syncthreads();
        s[t] += x;
        __syncthreads();
    }
    if (t < NSB) boff[t] = s[t] - v;
    if (t == NSB - 1) rowptr[N_NODES] = s[t];
}

__global__ __launch_bounds__(256) void scan3(const int* __restrict__ degi, const int* __restrict__ boff,
                                             int* __restrict__ rowptr, int* __restrict__ cursor,
                                             float* __restrict__ dinv) {
    __shared__ int s[256];
    int b = blockIdx.x, t = threadIdx.x;
    int idx = b * 256 + t;
    int v = (idx < N_NODES) ? degi[idx] : 0;
    s[t] = v;
    __syncthreads();
    for (int off = 1; off < 256; off <<= 1) {
        int x = (t >= off) ? s[t - off] : 0;
        __syncthreads();
        s[t] += x;
        __syncthreads();
    }
    if (idx < N_NODES) {
        int excl = s[t] - v + boff[b];
        rowptr[idx] = excl;
        cursor[idx] = excl;
        dinv[idx] = rsqrtf((float)v + 1.0f);   // +1 = self-loop
    }
}

__global__ void bin_edges(const int* __restrict__ src, const int* __restrict__ dst,
                          int* __restrict__ cursor, int* __restrict__ csrsrc) {
    int e = blockIdx.x * blockDim.x + threadIdx.x;
    if (e >= N_EDGES) return;
    int d = clampi(dst[e], N_NODES);
    int pos = atomicAdd(&cursor[d], 1);
    if (pos >= 0 && pos < N_EDGES) csrsrc[pos] = clampi(src[e], N_NODES);
}

// all 4 big weights: w[K][N] fp32 -> transposed fp16 [N][K], one launch
__global__ void split_wT4(const float* __restrict__ w2, const float* __restrict__ w3,
                          const float* __restrict__ wg1, const float* __restrict__ wg2,
                          _Float16* __restrict__ out) {
    int idx = blockIdx.x * blockDim.x + threadIdx.x;
    if (idx >= 4 * H * H) return;
    int l = idx / (H * H), r = idx % (H * H);
    const float* w = (l == 0) ? w2 : (l == 1) ? w3 : (l == 2) ? wg1 : wg2;
    int n = r % H, k = r / H;
    out[(size_t)l * H * H + (size_t)n * H + k] = (_Float16)w[(size_t)k * H + n];
}

// ---- fused GCN1: aggregate x (3-dim!) then matvec w1 + bias + relu + fp16 ----
__global__ void gcn1_fused(const int* __restrict__ rowptr, const int* __restrict__ csrsrc,
                           const float* __restrict__ x, const float* __restrict__ dinv,
                           const float* __restrict__ w1, const float* __restrict__ b1,
                           _Float16* __restrict__ hi) {
    int d = blockIdx.x * 2 + (threadIdx.x / 96);
    int t = threadIdx.x % 96;
    if (d >= N_NODES) return;
    float dd = dinv[d];
    float c = dd * dd;
    float s0 = x[d*3] * c, s1 = x[d*3+1] * c, s2 = x[d*3+2] * c;
    int beg = rowptr[d], end = rowptr[d + 1];
    for (int i = beg; i < end; i++) {
        int s = csrsrc[i];
        float cc = dinv[s] * dd;
        s0 += x[s*3] * cc; s1 += x[s*3+1] * cc; s2 += x[s*3+2] * cc;
    }
    int j0 = t * 8;
    h8 o;
    #pragma unroll
    for (int k = 0; k < 8; k++) {
        int j = j0 + k;
        float v = s0 * w1[j] + s1 * w1[H + j] + s2 * w1[2*H + j] + b1[j];
        o[k] = (_Float16)fmaxf(v, 0.f);
    }
    ((h8*)(hi + (size_t)d * H))[t] = o;
}

// ---- half-tile staging helpers for the 256^2 8-phase GEMM ----
// A half-tile = 128 rows x 64 K; all 8 waves stage it (2 gloads/thread).
// LDS slot layout (halfs): A slot(d,h) = (d*2+h)*8192 ; B slot(d,h) = 32768 + (d*2+h)*8192.
__device__ inline void stageA_half(const _Float16* __restrict__ a, _Float16* lds,
                                   int row0, int M, int wave, int lr, int cg,
                                   int d, int h, int s) {
    _Float16* base = lds + (d * 2 + h) * 8192;
    #pragma unroll
    for (int g = 0; g < 2; g++) {
        int r = row0 + h * 128 + g * 64 + wave * 8 + lr;
        if (r >= M) r = M - 1;                       // duplicate fetch, rows unused
        gload_lds16(a + (size_t)r * H + s * 64 + cg * 8, base + (g * 64 + wave * 8) * 64);
    }
}
__device__ inline void stageB_half(const _Float16* __restrict__ bt, _Float16* lds,
                                   int col0, int wave, int lr, int cg,
                                   int d, int h, int s) {
    _Float16* base = lds + 32768 + (d * 2 + h) * 8192;
    #pragma unroll
    for (int g = 0; g < 2; g++) {
        int r = col0 + h * 128 + g * 64 + wave * 8 + lr;   // <= 767, no clamp
        gload_lds16(bt + (size_t)r * H + s * 64 + cg * 8, base + (g * 64 + wave * 8) * 64);
    }
}

// -- fp16 MFMA GEMM: 256x256 tile, BK=64, 2dbuf x 2half LDS, 4 phases/K-tile --
// r24: faithful port of the verified m201 8-phase template (1563 TF @4k).
// R5 failure: 1024-thr block = min 4 waves/EU = 128 VGPR cap -> persistent-B
// spilled (VGPR=64, FETCH 10x, 287us). Back to 512 thr, launch_bounds(512,2)
// = 256 VGPR cap, 2 waves/SIMD (T5 role-split). 8 waves 2Mx4N, per-wave out
// 128x64 (acc[8][4] = 128 VGPR). Per K-tile 4 phases, each:
//   { ds_read subtile (0-12 b128) || stage 1 half-tile (2 gloads)
//     -> sched_bar -> s_barrier -> lgkm(0) -> sched_bar -> setprio(1)
//     16 MFMA setprio(0) -> sched_bar -> s_barrier }
// Reads: ph1 A(i0-3)+B(j0-1), ph2 B(j2-3), ph3 A(i4-7), ph4 none (reuse).
// Stages: ph1 A0(t+1), ph2 A1(t+1) [other dbuf, retired t-1 ph3];
//         ph3 B0(t+2), ph4 B1(t+2) [this dbuf's B fully read by end ph2].
// vmcnt(4) at ph4 (t<=9) certifies exactly tile t+1's 4 halves; vmcnt(0) at
// t=10; nothing outstanding at t=11. Never drains mid-loop (T4).
__global__ __launch_bounds__(512, 2) void gemm_f16(const _Float16* __restrict__ a,
                                                   const _Float16* __restrict__ bt,
                                                   _Float16* __restrict__ C, int M,
                                                   const float* __restrict__ asf,
                                                   const float* __restrict__ adf,
                                                   float* __restrict__ aS,
                                                   float* __restrict__ aD) {
    __shared__ alignas(16) _Float16 lds[65536];   // 128 KB: A 64 KB + B 64 KB

    int tid = threadIdx.x;
    int wave = tid >> 6, lane = tid & 63;
    int quad = lane >> 4, l16 = lane & 15;
    int wm = wave >> 2, wn = wave & 3;            // 2 row-waves x 4 col-waves

    int strip = blockIdx.x / 3, colt = blockIdx.x % 3;
    int row0 = strip * 256, col0 = colt * 256;
    int cw = col0 + wn * 64;                      // wave's 64-col slice = one head

    // staging lane geometry (pre-swizzled global source; r15/r24-verified)
    int lr = lane >> 3;
    int cg = (lane & 7) ^ lr;

    // fragment read constants: row&7 == l16&7 for all frag rows
    int swz = l16 & 7;
    int cx0 = (quad ^ swz) * 8;                   // kk=0 chunk offset (halfs)
    int cx1 = ((4 + quad) ^ swz) * 8;             // kk=1

    ffrag acc[8][4];
    #pragma unroll
    for (int i = 0; i < 8; i++)
        #pragma unroll
        for (int j = 0; j < 4; j++) { ffrag z = {0.f, 0.f, 0.f, 0.f}; acc[i][j] = z; }

    // ---- prologue: stage tile0 (4 halves) + B0(1),B1(1); certify tile0 ----
    stageA_half(a, lds, row0, M, wave, lr, cg, 0, 0, 0);   // A0(0)
    stageB_half(bt, lds, col0, wave, lr, cg, 0, 0, 0);     // B0(0)
    stageB_half(bt, lds, col0, wave, lr, cg, 0, 1, 0);     // B1(0)
    stageA_half(a, lds, row0, M, wave, lr, cg, 0, 1, 0);   // A1(0)
    stageB_half(bt, lds, col0, wave, lr, cg, 1, 0, 1);     // B0(1)
    stageB_half(bt, lds, col0, wave, lr, cg, 1, 1, 1);     // B1(1)
    asm volatile("s_waitcnt vmcnt(4)" ::: "memory");       // tile0 landed; B(1) in flight
    __builtin_amdgcn_s_barrier();

    #pragma unroll 1
    for (int t = 0; t < 12; t++) {
        int d = t & 1;
        const _Float16* pA = lds + (d * 2 + wm) * 8192;            // wave's A half-slot
        const _Float16* pB = lds + 32768 + (d * 2 + (wn >> 1)) * 8192;  // wave's B half-slot
        int brow = (wn & 1) * 64;                                   // B row base in slot

        h8 fa[4][2], fb0[2][2], fb1[2][2];

        // ========== phase 1: read A(i0-3)+B(j0-1); stage A0(t+1); MFMA q00 ==========
        #pragma unroll
        for (int i = 0; i < 4; i++) {
            fa[i][0] = *reinterpret_cast<const h8*>(pA + (i * 16 + l16) * 64 + cx0);
            fa[i][1] = *reinterpret_cast<const h8*>(pA + (i * 16 + l16) * 64 + cx1);
        }
        #pragma unroll
        for (int j = 0; j < 2; j++) {
            fb0[j][0] = *reinterpret_cast<const h8*>(pB + (brow + j * 16 + l16) * 64 + cx0);
            fb0[j][1] = *reinterpret_cast<const h8*>(pB + (brow + j * 16 + l16) * 64 + cx1);
        }
        if (t <= 10) stageA_half(a, lds, row0, M, wave, lr, cg, (t + 1) & 1, 0, t + 1);
        __builtin_amdgcn_sched_barrier(0);
        __builtin_amdgcn_s_barrier();
        asm volatile("s_waitcnt lgkmcnt(0)" ::: "memory");
        __builtin_amdgcn_sched_barrier(0);
        __builtin_amdgcn_s_setprio(1);
        #pragma unroll
        for (int kk = 0; kk < 2; kk++)
            #pragma unroll
            for (int i = 0; i < 4; i++)
                #pragma unroll
                for (int j = 0; j < 2; j++)
                    acc[i][j] = __builtin_amdgcn_mfma_f32_16x16x32_f16(fa[i][kk], fb0[j][kk], acc[i][j], 0, 0, 0);
        __builtin_amdgcn_s_setprio(0);
        __builtin_amdgcn_sched_barrier(0);
        __builtin_amdgcn_s_barrier();

        // ========== phase 2: read B(j2-3); stage A1(t+1); MFMA q01 ==========
        #pragma unroll
        for (int j = 0; j < 2; j++) {
            fb1[j][0] = *reinterpret_cast<const h8*>(pB + (brow + (2 + j) * 16 + l16) * 64 + cx0);
            fb1[j][1] = *reinterpret_cast<const h8*>(pB + (brow + (2 + j) * 16 + l16) * 64 + cx1);
        }
        if (t <= 10) stageA_half(a, lds, row0, M, wave, lr, cg, (t + 1) & 1, 1, t + 1);
        __builtin_amdgcn_sched_barrier(0);
        __builtin_amdgcn_s_barrier();
        asm volatile("s_waitcnt lgkmcnt(0)" ::: "memory");
        __builtin_amdgcn_sched_barrier(0);
        __builtin_amdgcn_s_setprio(1);
        #pragma unroll
        for (int kk = 0; kk < 2; kk++)
            #pragma unroll
            for (int i = 0; i < 4; i++)
                #pragma unroll
                for (int j = 0; j < 2; j++)
                    acc[i][2 + j] = __builtin_amdgcn_mfma_f32_16x16x32_f16(fa[i][kk], fb1[j][kk], acc[i][2 + j], 0, 0, 0);
        __builtin_amdgcn_s_setprio(0);
        __builtin_amdgcn_sched_barrier(0);
        __builtin_amdgcn_s_barrier();

        // ========== phase 3: read A(i4-7); stage B0(t+2); MFMA q11 ==========
        #pragma unroll
        for (int i = 0; i < 4; i++) {
            fa[i][0] = *reinterpret_cast<const h8*>(pA + ((4 + i) * 16 + l16) * 64 + cx0);
            fa[i][1] = *reinterpret_cast<const h8*>(pA + ((4 + i) * 16 + l16) * 64 + cx1);
        }
        if (t <= 9) stageB_half(bt, lds, col0, wave, lr, cg, d, 0, t + 2);
        __builtin_amdgcn_sched_barrier(0);
        __builtin_amdgcn_s_barrier();
        asm volatile("s_waitcnt lgkmcnt(0)" ::: "memory");
        __builtin_amdgcn_sched_barrier(0);
        __builtin_amdgcn_s_setprio(1);
        #pragma unroll
        for (int kk = 0; kk < 2; kk++)
            #pragma unroll
            for (int i = 0; i < 4; i++)
                #pragma unroll
                for (int j = 0; j < 2; j++)
                    acc[4 + i][2 + j] = __builtin_amdgcn_mfma_f32_16x16x32_f16(fa[i][kk], fb1[j][kk], acc[4 + i][2 + j], 0, 0, 0);
        __builtin_amdgcn_s_setprio(0);
        __builtin_amdgcn_sched_barrier(0);
        __builtin_amdgcn_s_barrier();

        // ========== phase 4: no reads; stage B1(t+2); MFMA q10; vmcnt ==========
        if (t <= 9) stageB_half(bt, lds, col0, wave, lr, cg, d, 1, t + 2);
        __builtin_amdgcn_sched_barrier(0);
        __builtin_amdgcn_s_barrier();
        __builtin_amdgcn_s_setprio(1);
        #pragma unroll
        for (int kk = 0; kk < 2; kk++)
            #pragma unroll
            for (int i = 0; i < 4; i++)
                #pragma unroll
                for (int j = 0; j < 2; j++)
                    acc[4 + i][j] = __builtin_amdgcn_mfma_f32_16x16x32_f16(fa[i][kk], fb0[j][kk], acc[4 + i][j], 0, 0, 0);
        __builtin_amdgcn_s_setprio(0);
        if (t <= 9)       asm volatile("s_waitcnt vmcnt(4)" ::: "memory");  // tile t+1 certified
        else if (t == 10) asm volatile("s_waitcnt vmcnt(0)" ::: "memory");  // tile 11 certified
        __builtin_amdgcn_sched_barrier(0);
        __builtin_amdgcn_s_barrier();
    }

    // epilogue: C/D layout col=lane&15, row=quad*4+reg (m89-verified); fp16 store
    #pragma unroll
    for (int i = 0; i < 8; i++)
        #pragma unroll
        for (int r = 0; r < 4; r++) {
            int row = row0 + wm * 128 + i * 16 + quad * 4 + r;
            if (row >= M) continue;
            #pragma unroll
            for (int j = 0; j < 4; j++)
                C[(size_t)row * H + cw + j * 16 + l16] = (_Float16)acc[i][j][r];
        }

    // fused GAT alpha: wave covers one full head (64 cols) for its 128 rows
    if (asf) {
        int head = colt * 4 + wn;
        float as_c[4], ad_c[4];
        #pragma unroll
        for (int j = 0; j < 4; j++) {
            as_c[j] = asf[cw + j * 16 + l16];
            ad_c[j] = adf[cw + j * 16 + l16];
        }
        #pragma unroll
        for (int i = 0; i < 8; i++)
            #pragma unroll
            for (int r = 0; r < 4; r++) {
                float ps = 0.f, pd = 0.f;
                #pragma unroll
                for (int j = 0; j < 4; j++) {
                    ps += acc[i][j][r] * as_c[j];
                    pd += acc[i][j][r] * ad_c[j];
                }
                ps += __shfl_xor(ps, 1);  pd += __shfl_xor(pd, 1);
                ps += __shfl_xor(ps, 2);  pd += __shfl_xor(pd, 2);
                ps += __shfl_xor(ps, 4);  pd += __shfl_xor(pd, 4);
                ps += __shfl_xor(ps, 8);  pd += __shfl_xor(pd, 8);
                int row = row0 + wm * 128 + i * 16 + quad * 4 + r;
                if (l16 == 0 && row < M) {
                    aS[row * NH + head] = ps;
                    aD[row * NH + head] = pd;
                }
            }
    }
}

// ------- fused GCN gather: 2 nodes/block, 16B h8 loads (r14-verified) --------
__global__ void gcn_gather(const int* __restrict__ rowptr, const int* __restrict__ csrsrc,
                           const _Float16* __restrict__ h, const float* __restrict__ dinv,
                           const float* __restrict__ bias, _Float16* __restrict__ hi) {
    int d = blockIdx.x * 2 + (threadIdx.x / 96);
    int t = threadIdx.x % 96;   // h8-chunk index (96 x 8 halves = 768)
    if (d >= N_NODES) return;
    float dd = dinv[d];
    float c = dd * dd;
    h8 v = ((const h8*)(h + (size_t)d * H))[t];
    float acc[8];
    #pragma unroll
    for (int k = 0; k < 8; k++) acc[k] = (float)v[k] * c;
    int beg = rowptr[d], end = rowptr[d + 1];
    for (int i = beg; i < end; i++) {
        int s = csrsrc[i];
        float cc = dinv[s] * dd;
        h8 u = ((const h8*)(h + (size_t)s * H))[t];
        #pragma unroll
        for (int k = 0; k < 8; k++) acc[k] += (float)u[k] * cc;
    }
    float4 b0 = ((const float4*)bias)[2 * t];
    float4 b1 = ((const float4*)bias)[2 * t + 1];
    h8 o;
    o[0] = (_Float16)fmaxf(acc[0] + b0.x, 0.f);
    o[1] = (_Float16)fmaxf(acc[1] + b0.y, 0.f);
    o[2] = (_Float16)fmaxf(acc[2] + b0.z, 0.f);
    o[3] = (_Float16)fmaxf(acc[3] + b0.w, 0.f);
    o[4] = (_Float16)fmaxf(acc[4] + b1.x, 0.f);
    o[5] = (_Float16)fmaxf(acc[5] + b1.y, 0.f);
    o[6] = (_Float16)fmaxf(acc[6] + b1.z, 0.f);
    o[7] = (_Float16)fmaxf(acc[7] + b1.w, 0.f);
    ((h8*)(hi + (size_t)d * H))[t] = o;
}

__device__ inline float lrelu(float v) { return (v > 0.f) ? v : 0.2f * v; }

// ---- GAT softmax stats: one thread per (node, head) (r18-verified) ----
__global__ void gat_stats(const int* __restrict__ rowptr, const int* __restrict__ csrsrc,
                          const float* __restrict__ aS, const float* __restrict__ aD,
                          float* __restrict__ selfc, float* __restrict__ coef) {
    int idx = blockIdx.x * blockDim.x + threadIdx.x;
    if (idx >= N_NODES * NH) return;
    int d = idx / NH, hh = idx % NH;
    int beg = rowptr[d], end = rowptr[d + 1];
    float adv = aD[idx];
    float eself = lrelu(aS[idx] + adv);
    float m = eself;
    for (int i = beg; i < end; i++)
        m = fmaxf(m, lrelu(aS[csrsrc[i] * NH + hh] + adv));
    float ssum = __expf(eself - m);
    for (int i = beg; i < end; i++)
        ssum += __expf(lrelu(aS[csrsrc[i] * NH + hh] + adv) - m);
    float inv = 1.0f / ssum;
    selfc[idx] = __expf(eself - m) * inv;
    for (int i = beg; i < end; i++)
        coef[(size_t)i * NH + hh] = __expf(lrelu(aS[csrsrc[i] * NH + hh] + adv) - m) * inv;
}

// fused GAT aggregation: single pass, precomputed coefficients; fp16 out.
__global__ void gat_gather(const int* __restrict__ rowptr, const int* __restrict__ csrsrc,
                           const _Float16* __restrict__ h, const float* __restrict__ selfc,
                           const float* __restrict__ coef, const float* __restrict__ bias,
                           _Float16* __restrict__ hi, int relu) {
    int d = blockIdx.x * 2 + (threadIdx.x / 96);
    int t = threadIdx.x % 96;
    if (d >= N_NODES) return;
    int hh = t >> 3;
    int beg = rowptr[d], end = rowptr[d + 1];
    float cself = selfc[d * NH + hh];
    h8 v = ((const h8*)(h + (size_t)d * H))[t];
    float acc[8];
    #pragma unroll
    for (int k = 0; k < 8; k++) acc[k] = (float)v[k] * cself;
    for (int i = beg; i < end; i++) {
        int s = csrsrc[i];
        float c = coef[(size_t)i * NH + hh];
        h8 u = ((const h8*)(h + (size_t)s * H))[t];
        #pragma unroll
        for (int k = 0; k < 8; k++) acc[k] += (float)u[k] * c;
    }
    float4 b0 = ((const float4*)bias)[2 * t];
    float4 b1 = ((const float4*)bias)[2 * t + 1];
    acc[0] += b0.x; acc[1] += b0.y; acc[2] += b0.z; acc[3] += b0.w;
    acc[4] += b1.x; acc[5] += b1.y; acc[6] += b1.z; acc[7] += b1.w;
    if (relu) {
        #pragma unroll
        for (int k = 0; k < 8; k++) acc[k] = fmaxf(acc[k], 0.f);
    }
    h8 o;
    #pragma unroll
    for (int k = 0; k < 8; k++) o[k] = (_Float16)acc[k];
    ((h8*)(hi + (size_t)d * H))[t] = o;
}

// ---------------- pooling (batch is sorted), two-stage + fused mlp1+mlp2 ------
__device__ inline int lower_bound_i(const int* b, int n, int key) {
    int lo = 0, hi = n;
    while (lo < hi) { int mid = (lo + hi) >> 1; if (b[mid] < key) lo = mid + 1; else hi = mid; }
    return lo;
}

__global__ void pool_partial(const int* __restrict__ batch, const _Float16* __restrict__ h,
                             float* __restrict__ ppool) {
    int g = blockIdx.x / PCH, c = blockIdx.x % PCH;
    int t = threadIdx.x;   // 0..191, h4v chunks
    int lo = lower_bound_i(batch, N_NODES, g);
    int hi = lower_bound_i(batch, N_NODES, g + 1);
    int len = hi - lo;
    int chunk = (len + PCH - 1) / PCH;
    int s = lo + c * chunk;
    int e = s + chunk; if (e > hi) e = hi;
    float4 a = {0, 0, 0, 0};
    for (int n = s; n < e; n++) {
        h4v v = ((const h4v*)(h + (size_t)n * H))[t];
        a.x += (float)v[0]; a.y += (float)v[1]; a.z += (float)v[2]; a.w += (float)v[3];
    }
    ((float4*)(ppool + (size_t)blockIdx.x * H))[t] = a;
}

// reduce partials -> mean row -> z = relu(row@wc1+bc1) -> logits = z@wc2+bc2
__global__ __launch_bounds__(384) void pool_mlp(const int* __restrict__ batch,
                                                const float* __restrict__ ppool,
                                                const float* __restrict__ wc1,
                                                const float* __restrict__ bc1,
                                                const float* __restrict__ wc2,
                                                const float* __restrict__ bc2,
                                                float* __restrict__ out) {
    __shared__ float row[H];
    __shared__ float z[H2];
    int g = blockIdx.x, t = threadIdx.x;   // 384 threads
    int lo = lower_bound_i(batch, N_NODES, g);
    int hi = lower_bound_i(batch, N_NODES, g + 1);
    float inv = 1.0f / fmaxf((float)(hi - lo), 1.0f);
    for (int c0 = t; c0 < H; c0 += 384) {
        float a = 0.f;
        for (int c = 0; c < PCH; c++) a += ppool[(size_t)(g * PCH + c) * H + c0];
        row[c0] = a * inv;
    }
    __syncthreads();
    float acc = bc1[t];
    for (int k = 0; k < H; k++) acc += row[k] * wc1[(size_t)k * H2 + t];
    z[t] = fmaxf(acc, 0.f);
    __syncthreads();
    if (t < NC) {
        float l = bc2[t];
        for (int k = 0; k < H2; k++) l += z[k] * wc2[(size_t)k * NC + t];
        out[g * NC + t] = l;
    }
}

// ---------------- launch ----------------
extern "C" void kernel_launch(void* const* d_in, const int* in_sizes, int n_in,
                              void* d_out, int out_size, void* d_ws, size_t ws_size,
                              hipStream_t stream) {
    (void)d_ws; (void)ws_size;
    const float* x     = (const float*)d_in[0];
    const int*   ei    = (const int*)d_in[1];
    const int*   batch = (const int*)d_in[2];
    const float* w1  = (const float*)d_in[3];  const float* b1  = (const float*)d_in[4];
    const float* w2  = (const float*)d_in[5];  const float* b2  = (const float*)d_in[6];
    const float* w3  = (const float*)d_in[7];  const float* b3  = (const float*)d_in[8];
    const float* wg1 = (const float*)d_in[9];  const float* as1 = (const float*)d_in[10];
    const float* ad1 = (const float*)d_in[11]; const float* bg1 = (const float*)d_in[12];
    const float* wg2 = (const float*)d_in[13]; const float* as2 = (const float*)d_in[14];
    const float* ad2 = (const float*)d_in[15]; const float* bg2 = (const float*)d_in[16];
    const float* wc1 = (const float*)d_in[17]; const float* bc1 = (const float*)d_in[18];
    const float* wc2 = (const float*)d_in[19]; const float* bc2 = (const float*)d_in[20];

    const int* srcp = ei;            // edge_index[0]
    const int* dstp = ei + N_EDGES;  // edge_index[1]

    float *dinv, *aS, *aD, *selfc, *coef, *ppool;
    _Float16 *ah, *ch, *wh;
    int *degi, *bsum, *boff, *cursor, *rowptr, *csrsrc;
    hipGetSymbolAddress((void**)&ah,     HIP_SYMBOL(g_ah));
    hipGetSymbolAddress((void**)&ch,     HIP_SYMBOL(g_ch));
    hipGetSymbolAddress((void**)&wh,     HIP_SYMBOL(g_wh));
    hipGetSymbolAddress((void**)&dinv,   HIP_SYMBOL(g_dinv));
    hipGetSymbolAddress((void**)&degi,   HIP_SYMBOL(g_degi));
    hipGetSymbolAddress((void**)&bsum,   HIP_SYMBOL(g_bsum));
    hipGetSymbolAddress((void**)&boff,   HIP_SYMBOL(g_boff));
    hipGetSymbolAddress((void**)&cursor, HIP_SYMBOL(g_cursor));
    hipGetSymbolAddress((void**)&rowptr, HIP_SYMBOL(g_rowptr));
    hipGetSymbolAddress((void**)&csrsrc, HIP_SYMBOL(g_csrsrc));
    hipGetSymbolAddress((void**)&aS,     HIP_SYMBOL(g_aS));
    hipGetSymbolAddress((void**)&aD,     HIP_SYMBOL(g_aD));
    hipGetSymbolAddress((void**)&selfc,  HIP_SYMBOL(g_selfc));
    hipGetSymbolAddress((void**)&coef,   HIP_SYMBOL(g_coef));
    hipGetSymbolAddress((void**)&ppool,  HIP_SYMBOL(g_ppool));

    auto cdiv = [](int a, int b) { return (a + b - 1) / b; };
    int ggrid = cdiv(N_NODES, 256) * (H / 256);                // 196*3 = 588
    int ngath = cdiv(N_NODES, 2);                              // 25000
    size_t HH = (size_t)H * H;

    // ---- weight transpose+cast, one launch, off the critical path ----
    split_wT4<<<cdiv(4*H*H,256),256,0,stream>>>(w2, w3, wg1, wg2, wh);

    // ---- CSR build (hierarchical scan) ----
    fill_i32<<<cdiv(N_NODES,256),256,0,stream>>>(degi, N_NODES, 0);
    count_deg<<<cdiv(N_EDGES,256),256,0,stream>>>(dstp, degi);
    scan1<<<NSB,256,0,stream>>>(degi, bsum);
    scan2<<<1,256,0,stream>>>(bsum, boff, rowptr);
    scan3<<<NSB,256,0,stream>>>(degi, boff, rowptr, cursor, dinv);
    bin_edges<<<cdiv(N_EDGES,256),256,0,stream>>>(srcp, dstp, cursor, csrsrc);

    // ---- GCN1: aggregate-first (3-dim) + matvec, single kernel ----
    gcn1_fused<<<ngath,192,0,stream>>>(rowptr, csrsrc, x, dinv, w1, b1, ah);

    // ---- GCN2 ----
    gemm_f16<<<ggrid,512,0,stream>>>(ah, wh + 0*HH, ch, N_NODES,
                                     (const float*)nullptr, (const float*)nullptr,
                                     (float*)nullptr, (float*)nullptr);
    gcn_gather<<<ngath,192,0,stream>>>(rowptr, csrsrc, ch, dinv, b2, ah);

    // ---- GCN3 ----
    gemm_f16<<<ggrid,512,0,stream>>>(ah, wh + 1*HH, ch, N_NODES,
                                     (const float*)nullptr, (const float*)nullptr,
                                     (float*)nullptr, (float*)nullptr);
    gcn_gather<<<ngath,192,0,stream>>>(rowptr, csrsrc, ch, dinv, b3, ah);

    // ---- GAT1 (alpha fused into GEMM; softmax precomputed; 1-pass gather) ----
    gemm_f16<<<ggrid,512,0,stream>>>(ah, wh + 2*HH, ch, N_NODES, as1, ad1, aS, aD);
    gat_stats<<<cdiv(N_NODES*NH,256),256,0,stream>>>(rowptr, csrsrc, aS, aD, selfc, coef);
    gat_gather<<<ngath,192,0,stream>>>(rowptr, csrsrc, ch, selfc, coef, bg1, ah, 1);

    // ---- GAT2 (no relu; fp16 out -> fp16 pooling) ----
    gemm_f16<<<ggrid,512,0,stream>>>(ah, wh + 3*HH, ch, N_NODES, as2, ad2, aS, aD);
    gat_stats<<<cdiv(N_NODES*NH,256),256,0,stream>>>(rowptr, csrsrc, aS, aD, selfc, coef);
    gat_gather<<<ngath,192,0,stream>>>(rowptr, csrsrc, ch, selfc, coef, bg2, ah, 0);

    // ---- pool (two-stage; stage-2 fused with mlp1+mlp2) ----
    pool_partial<<<NG*PCH,192,0,stream>>>(batch, ah, ppool);
    pool_mlp<<<NG,384,0,stream>>>(batch, ppool, wc1, bc1, wc2, bc2, (float*)d_out);
}